// Round 1
// baseline (107.226 us; speedup 1.0000x reference)
//
#include <hip/hip_runtime.h>
#include <hip/hip_bf16.h>
#include <math.h>

#define NPOS 8192
#define CIN 64
#define CQK 8
#define NB 2

typedef __attribute__((ext_vector_type(8))) short bf16x8;
typedef __attribute__((ext_vector_type(16))) float f32x16;

__device__ __forceinline__ unsigned short f2bf(float f) {
  union { float f; unsigned int u; } a; a.f = f;
  unsigned int r = a.u + 0x7FFFu + ((a.u >> 16) & 1u);
  return (unsigned short)(r >> 16);
}

// ---------------- QKV projection: x[B,64,N] f32 -> Q[B,N,8] K[B,N,8] V[B,64,N] bf16
__global__ __launch_bounds__(256) void qkv_proj(
    const float* __restrict__ x,
    const float* __restrict__ Wq, const float* __restrict__ bq,
    const float* __restrict__ Wk, const float* __restrict__ bk,
    const float* __restrict__ Wv, const float* __restrict__ bv,
    unsigned short* __restrict__ Qb, unsigned short* __restrict__ Kb,
    unsigned short* __restrict__ Vb) {
  __shared__ float sWq[CQK * CIN], sWk[CQK * CIN], sWv[CIN * CIN], sb[2 * CQK + CIN];
  int tid = threadIdx.x;
  for (int i = tid; i < CQK * CIN; i += 256) { sWq[i] = Wq[i]; sWk[i] = Wk[i]; }
  for (int i = tid; i < CIN * CIN; i += 256) sWv[i] = Wv[i];
  if (tid < CQK) sb[tid] = bq[tid];
  if (tid >= CQK && tid < 2 * CQK) sb[tid] = bk[tid - CQK];
  if (tid >= 2 * CQK && tid < 2 * CQK + CIN) sb[tid] = bv[tid - 2 * CQK];
  __syncthreads();

  int gid = blockIdx.x * 256 + tid;       // 0 .. B*N-1
  int b = gid >> 13;
  int n = gid & (NPOS - 1);
  const float* xp = x + (size_t)b * CIN * NPOS + n;
  float xv[CIN];
#pragma unroll
  for (int c = 0; c < CIN; ++c) xv[c] = xp[(size_t)c * NPOS];

  for (int o = 0; o < CQK; ++o) {
    float aq = sb[o], ak = sb[CQK + o];
#pragma unroll
    for (int c = 0; c < CIN; ++c) {
      aq += sWq[o * CIN + c] * xv[c];
      ak += sWk[o * CIN + c] * xv[c];
    }
    Qb[(size_t)gid * CQK + o] = f2bf(aq);
    Kb[(size_t)gid * CQK + o] = f2bf(ak);
  }
  for (int o = 0; o < CIN; ++o) {
    float av = sb[2 * CQK + o];
#pragma unroll
    for (int c = 0; c < CIN; ++c) av += sWv[o * CIN + c] * xv[c];
    Vb[((size_t)b * CIN + o) * NPOS + n] = f2bf(av);
  }
}

// ---------------- Flash attention: block = 32 queries, 8 waves split 8192 keys
__global__ __launch_bounds__(512, 4) void flash_attn(
    const unsigned short* __restrict__ Qb, const unsigned short* __restrict__ Kb,
    const unsigned short* __restrict__ Vb, const float* __restrict__ x,
    const float* __restrict__ gamma, float* __restrict__ out) {
  int tid = threadIdx.x;
  int wave = tid >> 6, lane = tid & 63;
  int qcol = lane & 31, hi = lane >> 5;
  int blk = blockIdx.x;
  int b = blk >> 8, qt = blk & 255;
  int qbase = qt * 32;

  // Q fragment (B-operand of QK mfma): col=lane&31=query, k = 8*hi+i (d, zero-padded 8..15)
  bf16x8 qfrag;
#pragma unroll
  for (int i = 0; i < 8; ++i) qfrag[i] = 0;
  if (!hi) qfrag = *reinterpret_cast<const bf16x8*>(
      Qb + ((size_t)b * NPOS + qbase + qcol) * CQK);

  f32x16 acc0, acc1;   // out^T[c][q]: acc0 c=0..31, acc1 c=32..63 (C-layout rows)
#pragma unroll
  for (int i = 0; i < 16; ++i) { acc0[i] = 0.f; acc1[i] = 0.f; }
  float m = -INFINITY, l = 0.f;

  const unsigned short* Kp = Kb + (size_t)b * NPOS * CQK;
  const unsigned short* Vp = Vb + (size_t)b * CIN * NPOS;
  const unsigned short* v0row = Vp + (size_t)qcol * NPOS;         // channel = qcol
  const unsigned short* v1row = Vp + (size_t)(32 + qcol) * NPOS;  // channel = 32+qcol

  int j0 = wave << 10;
  int jend = j0 + 1024;
  for (; j0 < jend; j0 += 32) {
    // K fragment (A-operand): row=lane&31=key, k=8*hi+i (d, zero-padded)
    bf16x8 kfrag;
#pragma unroll
    for (int i = 0; i < 8; ++i) kfrag[i] = 0;
    if (!hi) kfrag = *reinterpret_cast<const bf16x8*>(Kp + (size_t)(j0 + qcol) * CQK);
    f32x16 z;
#pragma unroll
    for (int i = 0; i < 16; ++i) z[i] = 0.f;
    // S^T[key][query]
    f32x16 S = __builtin_amdgcn_mfma_f32_32x32x16_bf16(kfrag, qfrag, z, 0, 0, 0);

    float tmax = S[0];
#pragma unroll
    for (int r = 1; r < 16; ++r) tmax = fmaxf(tmax, S[r]);
    tmax = fmaxf(tmax, __shfl_xor(tmax, 32));
    float mnew = fmaxf(m, tmax);
    float alpha = __expf(m - mnew);           // first iter: exp(-inf)=0
    float p[16];
    float lsum = 0.f;
#pragma unroll
    for (int r = 0; r < 16; ++r) { p[r] = __expf(S[r] - mnew); lsum += p[r]; }
    l = l * alpha + lsum;                     // lane-partial l (its 16 keys)
#pragma unroll
    for (int i = 0; i < 16; ++i) { acc0[i] *= alpha; acc1[i] *= alpha; }
    m = mnew;

    // pack P -> bf16 pairs; exchange with lane^32 to build B-operand fragments
    unsigned int u[8], w[8];
#pragma unroll
    for (int jj = 0; jj < 8; ++jj) {
      u[jj] = (unsigned int)f2bf(p[2 * jj]) | ((unsigned int)f2bf(p[2 * jj + 1]) << 16);
      w[jj] = __shfl_xor(u[jj], 32);
    }
    union { unsigned int ui[4]; bf16x8 v; } B0, B1;
    if (!hi) {
      B0.ui[0] = u[0]; B0.ui[1] = u[1]; B0.ui[2] = w[0]; B0.ui[3] = w[1];
      B1.ui[0] = u[4]; B1.ui[1] = u[5]; B1.ui[2] = w[4]; B1.ui[3] = w[5];
    } else {
      B0.ui[0] = w[2]; B0.ui[1] = w[3]; B0.ui[2] = u[2]; B0.ui[3] = u[3];
      B1.ui[0] = w[6]; B1.ui[1] = w[7]; B1.ui[2] = u[6]; B1.ui[3] = u[7];
    }

    // V fragments (A-operand): row=lane&31=channel, k=8*hi+i = key offset
    int koff = j0 + (hi << 3);
    bf16x8 va0 = *reinterpret_cast<const bf16x8*>(v0row + koff);
    bf16x8 va1 = *reinterpret_cast<const bf16x8*>(v0row + koff + 16);
    bf16x8 vb0 = *reinterpret_cast<const bf16x8*>(v1row + koff);
    bf16x8 vb1 = *reinterpret_cast<const bf16x8*>(v1row + koff + 16);
    acc0 = __builtin_amdgcn_mfma_f32_32x32x16_bf16(va0, B0.v, acc0, 0, 0, 0);
    acc0 = __builtin_amdgcn_mfma_f32_32x32x16_bf16(va1, B1.v, acc0, 0, 0, 0);
    acc1 = __builtin_amdgcn_mfma_f32_32x32x16_bf16(vb0, B0.v, acc1, 0, 0, 0);
    acc1 = __builtin_amdgcn_mfma_f32_32x32x16_bf16(vb1, B1.v, acc1, 0, 0, 0);
  }

  // -------- block-level merge of 8 wave-partials (LSE merge) --------
  __shared__ float sM[8][32], sL[8][32], sMfin[32], sLinv[32];
  __shared__ float sacc[64][32];
  for (int i = tid; i < CIN * 32; i += 512) (&sacc[0][0])[i] = 0.f;
  float lp = l + __shfl_xor(l, 32);
  if (!hi) { sM[wave][qcol] = m; sL[wave][qcol] = lp; }
  __syncthreads();
  if (tid < 32) {
    float M = -INFINITY;
    for (int w2 = 0; w2 < 8; ++w2) M = fmaxf(M, sM[w2][tid]);
    float L = 0.f;
    for (int w2 = 0; w2 < 8; ++w2) L += __expf(sM[w2][tid] - M) * sL[w2][tid];
    sMfin[tid] = M;
    sLinv[tid] = 1.0f / L;
  }
  __syncthreads();
  float f = __expf(m - sMfin[qcol]);
  for (int w2 = 0; w2 < 8; ++w2) {
    if (wave == w2) {
#pragma unroll
      for (int r = 0; r < 16; ++r) {
        int c = (r & 3) + ((r >> 2) << 3) + (hi << 2);
        sacc[c][qcol]      += acc0[r] * f;
        sacc[c + 32][qcol] += acc1[r] * f;
      }
    }
    __syncthreads();
  }
  float g = gamma[0];
  for (int i = tid; i < CIN * 32; i += 512) {
    int c = i >> 5, q = i & 31;
    size_t idx = ((size_t)b * CIN + c) * NPOS + qbase + q;
    out[idx] = g * sacc[c][q] * sLinv[q] + x[idx];
  }
}

extern "C" void kernel_launch(void* const* d_in, const int* in_sizes, int n_in,
                              void* d_out, int out_size, void* d_ws, size_t ws_size,
                              hipStream_t stream) {
  const float* x     = (const float*)d_in[0];
  const float* Wq    = (const float*)d_in[1];
  const float* bq    = (const float*)d_in[2];
  const float* Wk    = (const float*)d_in[3];
  const float* bk    = (const float*)d_in[4];
  const float* Wv    = (const float*)d_in[5];
  const float* bv    = (const float*)d_in[6];
  const float* gamma = (const float*)d_in[7];
  float* out = (float*)d_out;

  unsigned short* Qb = (unsigned short*)d_ws;                 // 2*8192*8 bf16 = 256 KB
  unsigned short* Kb = Qb + (size_t)NB * NPOS * CQK;          // 256 KB
  unsigned short* Vb = Kb + (size_t)NB * NPOS * CQK;          // 2*64*8192 bf16 = 2 MB

  qkv_proj<<<dim3(NB * NPOS / 256), dim3(256), 0, stream>>>(
      x, Wq, bq, Wk, bk, Wv, bv, Qb, Kb, Vb);
  flash_attn<<<dim3(NB * NPOS / 32), dim3(512), 0, stream>>>(
      Qb, Kb, Vb, x, gamma, out);
}